// Round 5
// baseline (693.714 us; speedup 1.0000x reference)
//
#include <hip/hip_runtime.h>
#include <math.h>

#define BB 256
#define TT 1024
#define KK 128
#define CHUNK 8
#define NCHUNK (TT / CHUNK)  // 128

typedef float v2f __attribute__((ext_vector_type(2)));

__global__ void zero_out_kernel(float* out) { out[0] = 0.0f; }

// One block per batch, 128 threads (2 waves). Thread tid owns output state
// j = tid: E column exp(trans[0..127][j]) lives in 64 float2 registers, and
// each step does z[j] = sum_i p[i]*E[i][j] as 64 v_pk_fma_f32 against
// wave-broadcast ds_read_b128 of the fp32 p vector in LDS. Renorm each step
// by the exact power-of-2 exponent of p_prev[0] (broadcast, wave-uniform).
// No shuffles, no unpack, one barrier per step.
__global__ __launch_bounds__(128) void crf_kernel(
    const float* __restrict__ inputs,      // B*T*K fp32
    const float* __restrict__ trans,       // K*K fp32
    const int* __restrict__ tags,          // B*T int32 view
    const int* __restrict__ mask,          // B*T int32
    float* __restrict__ out)               // scalar
{
    __shared__ __align__(16) float pbuf[2][KK];           // fp32 p, double-buffered
    __shared__ __align__(16) float ebuf[2][CHUNK * KK];   // exp(emissions)
    __shared__ float mbuf[2][CHUNK];
    __shared__ float sred[4];

    const int tid = threadIdx.x;   // == j, 0..127
    const int b   = blockIdx.x;

    const float* binp = inputs + (size_t)b * TT * KK;
    const int* bmask  = mask + (size_t)b * TT;
    const int* btags  = tags + (size_t)b * TT;

    // ---- E column in 64 float2 registers: E2[k] = exp(trans[2k..2k+1][j]) ----
    const float* tcol = trans + tid;
    v2f E2[64];
#pragma unroll
    for (int k = 0; k < 64; ++k) {
        E2[k].x = expf(tcol[(size_t)(2 * k) * KK]);
        E2[k].y = expf(tcol[(size_t)(2 * k + 1) * KK]);
    }

    // ---- stage chunk 0 of emissions as X = exp(e), + mask ----
    {
        float4 e0 = ((const float4*)binp)[tid];
        float4 e1 = ((const float4*)binp)[tid + 128];
        e0.x = __expf(e0.x); e0.y = __expf(e0.y); e0.z = __expf(e0.z); e0.w = __expf(e0.w);
        e1.x = __expf(e1.x); e1.y = __expf(e1.y); e1.z = __expf(e1.z); e1.w = __expf(e1.w);
        ((float4*)ebuf[0])[tid]       = e0;
        ((float4*)ebuf[0])[tid + 128] = e1;
    }
    if (tid < CHUNK) mbuf[0][tid] = (float)bmask[tid];
    __syncthreads();

    // ---- t = 0: p = exp(alpha0) = X[0][j], m = 0 ----
    float pcur = ebuf[0][tid];
    int m_int = 0;
    pbuf[0][tid] = pcur;
    __syncthreads();

    for (int c = 0; c < NCHUNK; ++c) {
        // prefetch next emission chunk into registers (exp applied at store)
        float4 ep0, ep1; int mpre = 0;
        if (c + 1 < NCHUNK) {
            const float4* src = (const float4*)(binp + (size_t)(c + 1) * CHUNK * KK);
            ep0 = src[tid];
            ep1 = src[tid + 128];
            if (tid < CHUNK) mpre = bmask[(c + 1) * CHUNK + tid];
        }
        const float* eb = ebuf[c & 1];
        const float* mb = mbuf[c & 1];
        const int s0 = (c == 0) ? 1 : 0;
        for (int s = s0; s < CHUNK; ++s) {
            const int t = c * CHUNK + s;
            const float4* pr4 = (const float4*)pbuf[(t - 1) & 1];
            float X  = eb[s * KK + tid];
            float mi = mb[s];
            float p00;
            v2f za = {0.f, 0.f}, zb = {0.f, 0.f}, zc = {0.f, 0.f}, zd = {0.f, 0.f};
#pragma unroll
            for (int r = 0; r < 8; ++r) {
                float4 pa = pr4[4 * r + 0];
                float4 pb = pr4[4 * r + 1];
                float4 pc = pr4[4 * r + 2];
                float4 pd = pr4[4 * r + 3];
                if (r == 0) p00 = pa.x;
                za = __builtin_elementwise_fma((v2f){pa.x, pa.y}, E2[8 * r + 0], za);
                zb = __builtin_elementwise_fma((v2f){pa.z, pa.w}, E2[8 * r + 1], zb);
                zc = __builtin_elementwise_fma((v2f){pb.x, pb.y}, E2[8 * r + 2], zc);
                zd = __builtin_elementwise_fma((v2f){pb.z, pb.w}, E2[8 * r + 3], zd);
                za = __builtin_elementwise_fma((v2f){pc.x, pc.y}, E2[8 * r + 4], za);
                zb = __builtin_elementwise_fma((v2f){pc.z, pc.w}, E2[8 * r + 5], zb);
                zc = __builtin_elementwise_fma((v2f){pd.x, pd.y}, E2[8 * r + 6], zc);
                zd = __builtin_elementwise_fma((v2f){pd.z, pd.w}, E2[8 * r + 7], zd);
            }
            v2f zz = (za + zb) + (zc + zd);
            float z = zz.x + zz.y;
            float pn = (mi != 0.0f) ? z * X : pcur;    // mask-hold (mi in {0,1})
            // renorm: exact pow2 from exponent of broadcast p_prev[0]
            int E0 = (int)((__float_as_uint(p00) >> 23) & 255u) - 127;
            float sc = __uint_as_float((unsigned)(127 - E0) << 23);   // 2^-E0
            pcur = pn * sc;
            m_int += E0;
            pbuf[t & 1][tid] = pcur;
            __syncthreads();
        }
        if (c + 1 < NCHUNK) {
            ep0.x = __expf(ep0.x); ep0.y = __expf(ep0.y); ep0.z = __expf(ep0.z); ep0.w = __expf(ep0.w);
            ep1.x = __expf(ep1.x); ep1.y = __expf(ep1.y); ep1.z = __expf(ep1.z); ep1.w = __expf(ep1.w);
            ((float4*)ebuf[(c + 1) & 1])[tid]       = ep0;
            ((float4*)ebuf[(c + 1) & 1])[tid + 128] = ep1;
            if (tid < CHUNK) mbuf[(c + 1) & 1][tid] = (float)mpre;
            __syncthreads();
        }
    }

    // ---- denominator: LSE_j(alpha_j) over 128 threads (2 waves) ----
    float a = (float)m_int * 0.69314718055994531f + logf(pcur);
    float v = a;
#pragma unroll
    for (int o = 1; o < 64; o <<= 1) v = fmaxf(v, __shfl_xor(v, o));
    if ((tid & 63) == 0) sred[tid >> 6] = v;
    __syncthreads();
    float mx = fmaxf(sred[0], sred[1]);
    float ev = __expf(a - mx);
#pragma unroll
    for (int o = 1; o < 64; o <<= 1) ev += __shfl_xor(ev, o);
    __syncthreads();
    if ((tid & 63) == 0) sred[tid >> 6] = ev;
    __syncthreads();
    float den = mx + logf(sred[0] + sred[1]);

    // ---- numerator (gold-path score) ----
    float numpart = 0.0f, maskpart = 0.0f;
#pragma unroll
    for (int kk = 0; kk < TT / 128; ++kk) {
        int t = tid + 128 * kk;
        int tg = btags[t];
        float mf = (float)bmask[t];
        maskpart += mf;
        if (t < TT - 1) {
            int tg1   = btags[t + 1];
            float mf1 = (float)bmask[t + 1];
            numpart += trans[tg * KK + tg1] * mf1;
            numpart += binp[(size_t)t * KK + tg] * mf;
        }
    }
#pragma unroll
    for (int o = 1; o < 64; o <<= 1) numpart += __shfl_xor(numpart, o);
#pragma unroll
    for (int o = 1; o < 64; o <<= 1) maskpart += __shfl_xor(maskpart, o);
    __syncthreads();
    if ((tid & 63) == 0) {
        sred[tid >> 6]     = numpart;
        sred[2 + (tid >> 6)] = maskpart;
    }
    __syncthreads();
    if (tid == 0) {
        float num  = sred[0] + sred[1];
        float msum = sred[2] + sred[3];
        int last_idx = (int)msum - 1;
        int ltag = btags[last_idx];
        num += binp[(size_t)(TT - 1) * KK + ltag] * (float)bmask[TT - 1];
        atomicAdd(out, num - den);
    }
}

extern "C" void kernel_launch(void* const* d_in, const int* in_sizes, int n_in,
                              void* d_out, int out_size, void* d_ws, size_t ws_size,
                              hipStream_t stream) {
    const float* inputs = (const float*)d_in[0];
    const float* trans  = (const float*)d_in[1];
    const int* tagsp    = (const int*)d_in[2];
    const int* maskp    = (const int*)d_in[3];
    float* out          = (float*)d_out;
    zero_out_kernel<<<1, 1, 0, stream>>>(out);
    crf_kernel<<<BB, 128, 0, stream>>>(inputs, trans, tagsp, maskp, out);
}